// Round 13
// baseline (120.361 us; speedup 1.0000x reference)
//
#include <hip/hip_runtime.h>

// Problem constants
#define NB     64      // batch
#define TT     2048    // time
#define INQ    8       // input size
#define CC     2       // channels
#define MM     10      // hidden m
#define ROWP   12      // padded row floats (48 B)
#define MATS   124     // matrix stride in LDS tree (124%32=28)
#define PSTR   20      // skp row stride floats (16B-aligned, conflict-benign)
#define SLEN   4       // sequential steps per pair segment
#define SEGS   128     // segments per block (256 thr / 2 lanes)
#define NCHUNK 4       // quarters per chain -> grid 512 = 1 clean round at 2 blocks/CU
#define NCHAIN (NB*CC)

typedef float v2f __attribute__((ext_vector_type(2)));

// Upper-triangle index for (k,j), k<j, into 45-element array
__device__ __forceinline__ constexpr int triIdx(int k, int j) {
    return k * 10 + j - ((k + 1) * (k + 2)) / 2;
}

// Swap with partner lane (lane ^ 1) via DPP quad_perm [1,0,3,2] = 0xB1
__device__ __forceinline__ float dpp_xor1(float v) {
    const int i = __float_as_int(v);
    const int r = __builtin_amdgcn_update_dpp(i, i, 0xB1, 0xF, 0xF, true);
    return __int_as_float(r);
}

// One Taylor row-stream (packed pair of rows): t = S*G; A = t; R += cj*t.
// Safe when S aliases A or R (t completed before writes). Row r of S*G
// depends only on row r of S, so in-place per-stream update is exact.
__device__ __forceinline__ void trow_pk(const float* __restrict__ Tri,
                                        v2f* A, v2f* R, const v2f* S, float cj) {
    v2f t[MM];
    t[0] = -S[1] * Tri[triIdx(0, 1)];
    #pragma unroll
    for (int j = 1; j < MM; ++j) t[j] = S[0] * Tri[triIdx(0, j)];
    #pragma unroll
    for (int k = 1; k < MM; ++k) {
        const v2f a = S[k];
        #pragma unroll
        for (int j = 0; j < MM; ++j) {
            if (k == j) continue;
            if (j == 0 && k == 1) continue;
            if (j > k) t[j] += a * Tri[triIdx(k, j)];
            else       t[j] -= a * Tri[triIdx(j, k)];
        }
    }
    #pragma unroll
    for (int j = 0; j < MM; ++j) { A[j] = t[j]; R[j] += cj * t[j]; }
}

__device__ __forceinline__ void trow_s(const float* __restrict__ Tri,
                                       float* A, float* R, const float* S, float cj) {
    float t[MM];
    t[0] = -S[1] * Tri[triIdx(0, 1)];
    #pragma unroll
    for (int j = 1; j < MM; ++j) t[j] = S[0] * Tri[triIdx(0, j)];
    #pragma unroll
    for (int k = 1; k < MM; ++k) {
        const float a = S[k];
        #pragma unroll
        for (int j = 0; j < MM; ++j) {
            if (k == j) continue;
            if (j == 0 && k == 1) continue;
            if (j > k) t[j] += a * Tri[triIdx(k, j)];
            else       t[j] -= a * Tri[triIdx(j, k)];
        }
    }
    #pragma unroll
    for (int j = 0; j < MM; ++j) { A[j] = t[j]; R[j] += cj * t[j]; }
}

// 2-lane pair combine: buf[ls] <- buf[ls] * buf[rs] (pq = which 5-row half)
__device__ __forceinline__ void pair_combine(float* buf_s, int ls, int rs, int pq) {
    float lrow[5][MM];
    #pragma unroll
    for (int r = 0; r < 5; ++r) {
        const float4* lr = reinterpret_cast<const float4*>(
            &buf_s[ls * MATS + (pq * 5 + r) * ROWP]);
        const float4 a = lr[0], b = lr[1], c4 = lr[2];
        lrow[r][0] = a.x;  lrow[r][1] = a.y;  lrow[r][2] = a.z;  lrow[r][3] = a.w;
        lrow[r][4] = b.x;  lrow[r][5] = b.y;  lrow[r][6] = b.z;  lrow[r][7] = b.w;
        lrow[r][8] = c4.x; lrow[r][9] = c4.y;
    }
    float d[5][MM];
    #pragma unroll
    for (int r = 0; r < 5; ++r)
        #pragma unroll
        for (int j = 0; j < MM; ++j)
            d[r][j] = 0.0f;
    #pragma unroll
    for (int k = 0; k < MM; ++k) {
        const float4* rr = reinterpret_cast<const float4*>(&buf_s[rs * MATS + k * ROWP]);
        const float4 a = rr[0], b = rr[1], c4 = rr[2];
        float rrow[MM];
        rrow[0] = a.x;  rrow[1] = a.y;  rrow[2] = a.z;  rrow[3] = a.w;
        rrow[4] = b.x;  rrow[5] = b.y;  rrow[6] = b.z;  rrow[7] = b.w;
        rrow[8] = c4.x; rrow[9] = c4.y;
        #pragma unroll
        for (int r = 0; r < 5; ++r) {
            const float lv = lrow[r][k];
            #pragma unroll
            for (int j = 0; j < MM; ++j)
                d[r][j] += lv * rrow[j];
        }
    }
    float* dst = &buf_s[ls * MATS + pq * 5 * ROWP];
    #pragma unroll
    for (int r = 0; r < 5; ++r) {
        float4* drow = reinterpret_cast<float4*>(dst + r * ROWP);
        drow[0] = make_float4(d[r][0], d[r][1], d[r][2], d[r][3]);
        drow[1] = make_float4(d[r][4], d[r][5], d[r][6], d[r][7]);
        drow[2] = make_float4(d[r][8], d[r][9], 0.0f, 0.0f);
    }
}

// One block per (chain, quarter). LANE PAIR owns a segment (SLEN=4 steps);
// lane p holds rows 5p..5p+4 as 2 packed pairs + 1 scalar row: 10 row-units
// per matrix-step exact (quad layout burned 12) and each wave advances 32
// matrix-steps/iter instead of 16 -> ~30% fewer serial issues. Tri exchange
// via xor-1 DPP + cndmask (45+45 per lane = same device cost as quad's
// 4x45 dpp). In-place per-row Horner (no Acc copies array juggling).
// Live ~200 VGPR -> still the 2-waves/SIMD level (cliff at 256); plain
// launch_bounds(256) is the only allocator-safe config (r4/r8).
__global__ __launch_bounds__(256)
void dev_serial(const float* __restrict__ x,
                const float* __restrict__ A,
                float* __restrict__ ws)
{
    __shared__ __align__(16) float skp_s[24 * PSTR];    // 1920 B
    __shared__ __align__(16) float buf_s[SEGS * MATS];  // 63488 B (total 65408 <= 64K)

    const int tid   = threadIdx.x;
    const int chain = blockIdx.x >> 2;   // / NCHUNK
    const int qt    = blockIdx.x & 3;
    const int n     = chain >> 1;        // / CC
    const int c     = chain & 1;

    // skp row r (r = p*12+pp) holds v2f{ tri(24p+2pp), tri(24p+2pp+1) } per
    // input ip at float offset 2*ip+h; tri indices >=45 are zero.
    for (int e = tid; e < 24 * 16; e += 256) {
        const int r   = e >> 4;
        const int rem = e & 15;
        const int ip  = rem >> 1;
        const int h   = rem & 1;
        const int t   = 24 * (r / 12) + 2 * (r % 12) + h;
        float v = 0.0f;
        if (t < 45) {
            int k = 0, r2 = t;
            while (r2 >= 9 - k) { r2 -= (9 - k); ++k; }
            const int j = k + 1 + r2;
            const float* Ab = A + (size_t)(c * INQ + ip) * (MM * MM);
            v = Ab[k * MM + j] - Ab[j * MM + k];
        }
        skp_s[r * PSTR + 2 * ip + h] = v;
    }
    for (int r = tid; r < 24; r += 256) {
        skp_s[r * PSTR + 16] = 0.0f; skp_s[r * PSTR + 17] = 0.0f;
        skp_s[r * PSTR + 18] = 0.0f; skp_s[r * PSTR + 19] = 0.0f;
    }
    __syncthreads();

    const int seg = tid >> 1;
    const int p   = tid & 1;             // lane within pair; rows 5p..5p+4
    const int r5  = 5 * p;

    // Running product: rows {r5,r5+1} pk, {r5+2,r5+3} pk, {r5+4} scalar
    v2f   Rp0[MM], Rp1[MM];
    float Rs[MM];
    #pragma unroll
    for (int j = 0; j < MM; ++j) {
        Rp0[j] = (v2f){ (j == r5)     ? 1.0f : 0.0f, (j == r5 + 1) ? 1.0f : 0.0f };
        Rp1[j] = (v2f){ (j == r5 + 2) ? 1.0f : 0.0f, (j == r5 + 3) ? 1.0f : 0.0f };
        Rs[j]  = (j == r5 + 4) ? 1.0f : 0.0f;
    }

    const float* xb = x + (size_t)n * TT * INQ;
    const int t0 = qt * (SEGS * SLEN) + seg * SLEN;   // max t0+3 = 2047

    // Pipelined x
    float4 cur0, cur1, nxt0, nxt1;
    {
        const float4* pp = reinterpret_cast<const float4*>(xb + (size_t)t0 * INQ);
        cur0 = pp[0]; cur1 = pp[1];
        int t1 = t0 + 1; if (t1 > TT - 1) t1 = TT - 1;
        const float4* pn = reinterpret_cast<const float4*>(xb + (size_t)t1 * INQ);
        nxt0 = pn[0]; nxt1 = pn[1];
    }

    #pragma unroll 1
    for (int s = 0; s < SLEN; ++s) {
        float dx[INQ];
        dx[0] = nxt0.x - cur0.x; dx[1] = nxt0.y - cur0.y;
        dx[2] = nxt0.z - cur0.z; dx[3] = nxt0.w - cur0.w;
        dx[4] = nxt1.x - cur1.x; dx[5] = nxt1.y - cur1.y;
        dx[6] = nxt1.z - cur1.z; dx[7] = nxt1.w - cur1.w;
        cur0 = nxt0; cur1 = nxt1;
        {
            int t2 = t0 + s + 2; if (t2 > TT - 1) t2 = TT - 1;
            const float4* pn = reinterpret_cast<const float4*>(xb + (size_t)t2 * INQ);
            nxt0 = pn[0]; nxt1 = pn[1];
        }

        // My 24 tri values (packed): tv[u] = tri(24p + u)
        float tv[24];
        #pragma unroll
        for (int pp = 0; pp < 12; ++pp) {
            const v2f* sp = reinterpret_cast<const v2f*>(&skp_s[(p * 12 + pp) * PSTR]);
            v2f acc = dx[0] * sp[0];
            #pragma unroll
            for (int ip = 1; ip < INQ; ++ip)
                acc += dx[ip] * sp[ip];
            tv[2 * pp] = acc.x; tv[2 * pp + 1] = acc.y;
        }

        // Assemble Tri[45]: owner lane U/24 holds tri U at tv[U%24];
        // 1 dpp + 1 cndmask per entry (select direction known at compile time).
        float Tri[45];
        #define TRIFILL(U) {                                                   \
            const float own = tv[(U) % 24];                                    \
            const float rec = dpp_xor1(own);                                   \
            Tri[U] = ((U) / 24 == 0) ? (p ? rec : own) : (p ? own : rec);      \
        }
        TRIFILL(0)  TRIFILL(1)  TRIFILL(2)  TRIFILL(3)  TRIFILL(4)
        TRIFILL(5)  TRIFILL(6)  TRIFILL(7)  TRIFILL(8)  TRIFILL(9)
        TRIFILL(10) TRIFILL(11) TRIFILL(12) TRIFILL(13) TRIFILL(14)
        TRIFILL(15) TRIFILL(16) TRIFILL(17) TRIFILL(18) TRIFILL(19)
        TRIFILL(20) TRIFILL(21) TRIFILL(22) TRIFILL(23) TRIFILL(24)
        TRIFILL(25) TRIFILL(26) TRIFILL(27) TRIFILL(28) TRIFILL(29)
        TRIFILL(30) TRIFILL(31) TRIFILL(32) TRIFILL(33) TRIFILL(34)
        TRIFILL(35) TRIFILL(36) TRIFILL(37) TRIFILL(38) TRIFILL(39)
        TRIFILL(40) TRIFILL(41) TRIFILL(42) TRIFILL(43) TRIFILL(44)
        #undef TRIFILL

        // Unnormalized ascending Horner: A_j = A_{j-1}*G; R += (1/j!)*A_j
        v2f   Ap0[MM], Ap1[MM];
        float As[MM];
        trow_pk(Tri, Ap0, Rp0, Rp0, 1.0f);
        trow_pk(Tri, Ap1, Rp1, Rp1, 1.0f);
        trow_s (Tri, As,  Rs,  Rs,  1.0f);
        trow_pk(Tri, Ap0, Rp0, Ap0, 0.5f);
        trow_pk(Tri, Ap1, Rp1, Ap1, 0.5f);
        trow_s (Tri, As,  Rs,  As,  0.5f);
        trow_pk(Tri, Ap0, Rp0, Ap0, 0.16666667f);
        trow_pk(Tri, Ap1, Rp1, Ap1, 0.16666667f);
        trow_s (Tri, As,  Rs,  As,  0.16666667f);
        trow_pk(Tri, Ap0, Rp0, Ap0, 0.041666668f);
        trow_pk(Tri, Ap1, Rp1, Ap1, 0.041666668f);
        trow_s (Tri, As,  Rs,  As,  0.041666668f);
        trow_pk(Tri, Ap0, Rp0, Ap0, 0.0083333338f);
        trow_pk(Tri, Ap1, Rp1, Ap1, 0.0083333338f);
        trow_s (Tri, As,  Rs,  As,  0.0083333338f);
        trow_pk(Tri, Ap0, Rp0, Ap0, 0.0013888889f);
        trow_pk(Tri, Ap1, Rp1, Ap1, 0.0013888889f);
        trow_s (Tri, As,  Rs,  As,  0.0013888889f);
    }

    // Store segment product rows 5p..5p+4
    {
        float* dst = &buf_s[seg * MATS];
        float4* d0 = reinterpret_cast<float4*>(dst + (r5 + 0) * ROWP);
        d0[0] = make_float4(Rp0[0].x, Rp0[1].x, Rp0[2].x, Rp0[3].x);
        d0[1] = make_float4(Rp0[4].x, Rp0[5].x, Rp0[6].x, Rp0[7].x);
        d0[2] = make_float4(Rp0[8].x, Rp0[9].x, 0.0f, 0.0f);
        float4* d1 = reinterpret_cast<float4*>(dst + (r5 + 1) * ROWP);
        d1[0] = make_float4(Rp0[0].y, Rp0[1].y, Rp0[2].y, Rp0[3].y);
        d1[1] = make_float4(Rp0[4].y, Rp0[5].y, Rp0[6].y, Rp0[7].y);
        d1[2] = make_float4(Rp0[8].y, Rp0[9].y, 0.0f, 0.0f);
        float4* d2 = reinterpret_cast<float4*>(dst + (r5 + 2) * ROWP);
        d2[0] = make_float4(Rp1[0].x, Rp1[1].x, Rp1[2].x, Rp1[3].x);
        d2[1] = make_float4(Rp1[4].x, Rp1[5].x, Rp1[6].x, Rp1[7].x);
        d2[2] = make_float4(Rp1[8].x, Rp1[9].x, 0.0f, 0.0f);
        float4* d3 = reinterpret_cast<float4*>(dst + (r5 + 3) * ROWP);
        d3[0] = make_float4(Rp1[0].y, Rp1[1].y, Rp1[2].y, Rp1[3].y);
        d3[1] = make_float4(Rp1[4].y, Rp1[5].y, Rp1[6].y, Rp1[7].y);
        d3[2] = make_float4(Rp1[8].y, Rp1[9].y, 0.0f, 0.0f);
        float4* d4 = reinterpret_cast<float4*>(dst + (r5 + 4) * ROWP);
        d4[0] = make_float4(Rs[0], Rs[1], Rs[2], Rs[3]);
        d4[1] = make_float4(Rs[4], Rs[5], Rs[6], Rs[7]);
        d4[2] = make_float4(Rs[8], Rs[9], 0.0f, 0.0f);
    }
    __syncthreads();

    // Dyadic pair tree over 128 slots, 6 levels -> survivors at 0 and 64
    #pragma unroll 1
    for (int span = 2; span <= 64; span <<= 1) {
        const int np = SEGS / span;
        if (tid < 2 * np) {
            const int pr = tid >> 1;
            const int pq = tid & 1;
            pair_combine(buf_s, pr * span, pr * span + (span >> 1), pq);
        }
        __syncthreads();
    }

    // Two half-quarter products -> ws (time order: slot 0 then slot 64)
    if (tid < 60) {
        const int m  = tid / 30;
        const int o4 = tid - m * 30;
        const float4 v = reinterpret_cast<const float4*>(&buf_s[(m * 64) * MATS])[o4];
        reinterpret_cast<float4*>(ws)[(((size_t)chain * 4 + qt) * 2 + m) * 30 + o4] = v;
    }
}

// K2: one block per chain; combine its 8 half-quarter products (time order)
__global__ __launch_bounds__(256)
void dev_tree8(const float* __restrict__ ws, float* __restrict__ out)
{
    __shared__ __align__(16) float buf_s[8 * MATS];
    const int tid   = threadIdx.x;
    const int chain = blockIdx.x;

    if (tid < 240) {
        const int m  = tid / 30;
        const int o4 = tid - m * 30;
        const float4 v = reinterpret_cast<const float4*>(ws)[((size_t)chain * 8 + m) * 30 + o4];
        reinterpret_cast<float4*>(&buf_s[m * MATS])[o4] = v;
    }
    __syncthreads();

    #pragma unroll 1
    for (int span = 2; span <= 8; span <<= 1) {
        const int np = 8 / span;
        if (tid < 2 * np) {
            const int pr = tid >> 1;
            const int pq = tid & 1;
            pair_combine(buf_s, pr * span, pr * span + (span >> 1), pq);
        }
        __syncthreads();
    }

    if (tid < 100) {
        const int i = tid / 10;
        const int j = tid - i * 10;
        out[(size_t)chain * 100 + tid] = buf_s[i * ROWP + j];
    }
}

extern "C" void kernel_launch(void* const* d_in, const int* in_sizes, int n_in,
                              void* d_out, int out_size, void* d_ws, size_t ws_size,
                              hipStream_t stream) {
    (void)in_sizes; (void)n_in; (void)out_size; (void)ws_size;
    const float* x = (const float*)d_in[0];  // (64, 2048, 8)
    const float* A = (const float*)d_in[1];  // (2, 8, 10, 10)
    float* out = (float*)d_out;              // (64, 2, 10, 10)
    float* ws  = (float*)d_ws;               // 1024 mats * 480 B = 491,520 B

    dev_serial<<<dim3(NCHAIN * NCHUNK), dim3(256), 0, stream>>>(x, A, ws);
    dev_tree8<<<dim3(NCHAIN), dim3(256), 0, stream>>>(ws, out);
}

// Round 14
// 108.896 us; speedup vs baseline: 1.1053x; 1.1053x over previous
//
#include <hip/hip_runtime.h>

// Problem constants
#define NB     64      // batch
#define TT     2048    // time
#define INQ    8       // input size
#define CC     2       // channels
#define MM     10      // hidden m
#define ROWP   12      // padded row floats (48 B)
#define MATS   124     // matrix stride in LDS tree (124%32=28)
#define PSTR   20      // skp row stride floats (16B-aligned)
#define SLEN   8       // sequential steps per quad segment
#define SEGS   64      // segments per block (256 thr / 4 lanes)
#define NCHUNK 4       // quarters per chain -> grid 512 = 1 clean round at 2 blocks/CU
#define NCHAIN (NB*CC)

typedef float v2f __attribute__((ext_vector_type(2)));

// Upper-triangle index for (k,j), k<j, into 45-element array
__device__ __forceinline__ constexpr int triIdx(int k, int j) {
    return k * 10 + j - ((k + 1) * (k + 2)) / 2;
}

// Broadcast lane (quad base + SRC)'s value to all 4 lanes of the quad.
template <int SRC>
__device__ __forceinline__ float dpp_qbcast(float v) {
    const int i = __float_as_int(v);
    const int r = __builtin_amdgcn_update_dpp(i, i, SRC * 0x55, 0xF, 0xF, true);
    return __int_as_float(r);
}

// One Taylor row-stream, packed pair of rows: t = S*G; A = t; R += cj*t.
// Row r of S*G depends only on row r of S -> in-place safe (S may alias A).
__device__ __forceinline__ void trow_pk(const float* __restrict__ Tri,
                                        v2f* A, v2f* R, const v2f* S, float cj) {
    v2f t[MM];
    t[0] = -S[1] * Tri[triIdx(0, 1)];
    #pragma unroll
    for (int j = 1; j < MM; ++j) t[j] = S[0] * Tri[triIdx(0, j)];
    #pragma unroll
    for (int k = 1; k < MM; ++k) {
        const v2f a = S[k];
        #pragma unroll
        for (int j = 0; j < MM; ++j) {
            if (k == j) continue;
            if (j == 0 && k == 1) continue;
            if (j > k) t[j] += a * Tri[triIdx(k, j)];
            else       t[j] -= a * Tri[triIdx(j, k)];
        }
    }
    #pragma unroll
    for (int j = 0; j < MM; ++j) { A[j] = t[j]; R[j] += cj * t[j]; }
}

__device__ __forceinline__ void trow_s(const float* __restrict__ Tri,
                                       float* A, float* R, const float* S, float cj) {
    float t[MM];
    t[0] = -S[1] * Tri[triIdx(0, 1)];
    #pragma unroll
    for (int j = 1; j < MM; ++j) t[j] = S[0] * Tri[triIdx(0, j)];
    #pragma unroll
    for (int k = 1; k < MM; ++k) {
        const float a = S[k];
        #pragma unroll
        for (int j = 0; j < MM; ++j) {
            if (k == j) continue;
            if (j == 0 && k == 1) continue;
            if (j > k) t[j] += a * Tri[triIdx(k, j)];
            else       t[j] -= a * Tri[triIdx(j, k)];
        }
    }
    #pragma unroll
    for (int j = 0; j < MM; ++j) { A[j] = t[j]; R[j] += cj * t[j]; }
}

// 2-lane pair combine: buf[ls] <- buf[ls] * buf[rs] (pq = which 5-row half)
__device__ __forceinline__ void pair_combine(float* buf_s, int ls, int rs, int pq) {
    float lrow[5][MM];
    #pragma unroll
    for (int r = 0; r < 5; ++r) {
        const float4* lr = reinterpret_cast<const float4*>(
            &buf_s[ls * MATS + (pq * 5 + r) * ROWP]);
        const float4 a = lr[0], b = lr[1], c4 = lr[2];
        lrow[r][0] = a.x;  lrow[r][1] = a.y;  lrow[r][2] = a.z;  lrow[r][3] = a.w;
        lrow[r][4] = b.x;  lrow[r][5] = b.y;  lrow[r][6] = b.z;  lrow[r][7] = b.w;
        lrow[r][8] = c4.x; lrow[r][9] = c4.y;
    }
    float d[5][MM];
    #pragma unroll
    for (int r = 0; r < 5; ++r)
        #pragma unroll
        for (int j = 0; j < MM; ++j)
            d[r][j] = 0.0f;
    #pragma unroll
    for (int k = 0; k < MM; ++k) {
        const float4* rr = reinterpret_cast<const float4*>(&buf_s[rs * MATS + k * ROWP]);
        const float4 a = rr[0], b = rr[1], c4 = rr[2];
        float rrow[MM];
        rrow[0] = a.x;  rrow[1] = a.y;  rrow[2] = a.z;  rrow[3] = a.w;
        rrow[4] = b.x;  rrow[5] = b.y;  rrow[6] = b.z;  rrow[7] = b.w;
        rrow[8] = c4.x; rrow[9] = c4.y;
        #pragma unroll
        for (int r = 0; r < 5; ++r) {
            const float lv = lrow[r][k];
            #pragma unroll
            for (int j = 0; j < MM; ++j)
                d[r][j] += lv * rrow[j];
        }
    }
    float* dst = &buf_s[ls * MATS + pq * 5 * ROWP];
    #pragma unroll
    for (int r = 0; r < 5; ++r) {
        float4* drow = reinterpret_cast<float4*>(dst + r * ROWP);
        drow[0] = make_float4(d[r][0], d[r][1], d[r][2], d[r][3]);
        drow[1] = make_float4(d[r][4], d[r][5], d[r][6], d[r][7]);
        drow[2] = make_float4(d[r][8], d[r][9], 0.0f, 0.0f);
    }
}

// One block per (chain, quarter) — r12 structure (best base: 67.4 µs serial,
// grid 512 = one clean round at the 2-waves/SIMD level; VGPR cliffs at
// {64,128,256} put all 136-256 variants on 2 waves — r13's pair split hit
// 256 VGPR + spills and lost its 17% work saving). Taylor: quad rows
// q0 pk{0,1}+s{2}, q1 pk{3,4}+s{5}, q2 pk{6,7}, q3 pk{8,9} (q2/q3 scalar
// stream is dummy row 9). KTAY=5 this round: ||G||^6/720 ~1.5e-6/step
// trunc, ~3e-3 accumulated — inside the 1.95e-2 budget (measure absmax!).
__global__ __launch_bounds__(256)
void dev_serial(const float* __restrict__ x,
                const float* __restrict__ A,
                float* __restrict__ ws)
{
    __shared__ __align__(16) float skp_s[24 * PSTR];    // 1920 B pair-interleaved
    __shared__ __align__(16) float buf_s[SEGS * MATS];  // 31744 B tree buffer

    const int tid   = threadIdx.x;
    const int chain = blockIdx.x >> 2;   // / NCHUNK
    const int qt    = blockIdx.x & 3;
    const int n     = chain >> 1;        // / CC
    const int c     = chain & 1;

    // skp[p][ip] = v2f{ sktri[2p][ip], sktri[2p+1][ip] }, rows >=45 zero.
    for (int e = tid; e < 24 * 16; e += 256) {
        const int p   = e >> 4;
        const int rem = e & 15;
        const int ip  = rem >> 1;
        const int h   = rem & 1;
        const int t   = 2 * p + h;
        float v = 0.0f;
        if (t < 45) {
            int k = 0, r2 = t;
            while (r2 >= 9 - k) { r2 -= (9 - k); ++k; }
            const int j = k + 1 + r2;
            const float* Ab = A + (size_t)(c * INQ + ip) * (MM * MM);
            v = Ab[k * MM + j] - Ab[j * MM + k];
        }
        skp_s[p * PSTR + 2 * ip + h] = v;
    }
    for (int p = tid; p < 24; p += 256) {
        skp_s[p * PSTR + 16] = 0.0f; skp_s[p * PSTR + 17] = 0.0f;
        skp_s[p * PSTR + 18] = 0.0f; skp_s[p * PSTR + 19] = 0.0f;
    }
    __syncthreads();

    const int seg = tid >> 2;
    const int q   = tid & 3;                        // lane within quad
    const int p0  = (q < 2) ? 3 * q : (q == 2 ? 6 : 8);  // packed pair rows
    const int sr  = (q < 2) ? (3 * q + 2) : 9;      // scalar row (dummy on q>=2)
    const bool hasS = (q < 2);

    v2f   R01[MM];
    float R2[MM];
    #pragma unroll
    for (int j = 0; j < MM; ++j) {
        R01[j] = (v2f){ (j == p0) ? 1.0f : 0.0f, (j == p0 + 1) ? 1.0f : 0.0f };
        R2[j]  = (j == sr) ? 1.0f : 0.0f;
    }

    const float* xb = x + (size_t)n * TT * INQ;
    const int t0 = qt * (SEGS * SLEN) + seg * SLEN;   // max t0+7 = 2047

    // Pipelined x
    float4 cur0, cur1, nxt0, nxt1;
    {
        const float4* p = reinterpret_cast<const float4*>(xb + (size_t)t0 * INQ);
        cur0 = p[0]; cur1 = p[1];
        int t1 = t0 + 1; if (t1 > TT - 1) t1 = TT - 1;
        const float4* pn = reinterpret_cast<const float4*>(xb + (size_t)t1 * INQ);
        nxt0 = pn[0]; nxt1 = pn[1];
    }

    #pragma unroll 1
    for (int s = 0; s < SLEN; ++s) {
        float dx[INQ];
        dx[0] = nxt0.x - cur0.x; dx[1] = nxt0.y - cur0.y;
        dx[2] = nxt0.z - cur0.z; dx[3] = nxt0.w - cur0.w;
        dx[4] = nxt1.x - cur1.x; dx[5] = nxt1.y - cur1.y;
        dx[6] = nxt1.z - cur1.z; dx[7] = nxt1.w - cur1.w;
        cur0 = nxt0; cur1 = nxt1;
        {
            int t2 = t0 + s + 2; if (t2 > TT - 1) t2 = TT - 1;
            const float4* pn = reinterpret_cast<const float4*>(xb + (size_t)t2 * INQ);
            nxt0 = pn[0]; nxt1 = pn[1];
        }

        // Packed tv: tvp[pp] = (tri[12q+2pp], tri[12q+2pp+1])
        v2f tvp[6];
        #pragma unroll
        for (int pp = 0; pp < 6; ++pp) {
            const v2f* sp = reinterpret_cast<const v2f*>(&skp_s[(6 * q + pp) * PSTR]);
            v2f acc = dx[0] * sp[0];
            #pragma unroll
            for (int ip = 1; ip < INQ; ++ip)
                acc += dx[ip] * sp[ip];
            tvp[pp] = acc;
        }
        float tv[12];
        #pragma unroll
        for (int pp = 0; pp < 6; ++pp) { tv[2 * pp] = tvp[pp].x; tv[2 * pp + 1] = tvp[pp].y; }

        // Assemble Tri[45] per-lane via DPP quad broadcast
        float Tri[45];
        #define TRIFILL(U) Tri[U] = dpp_qbcast<(U) / 12>(tv[(U) % 12]);
        TRIFILL(0)  TRIFILL(1)  TRIFILL(2)  TRIFILL(3)  TRIFILL(4)
        TRIFILL(5)  TRIFILL(6)  TRIFILL(7)  TRIFILL(8)  TRIFILL(9)
        TRIFILL(10) TRIFILL(11) TRIFILL(12) TRIFILL(13) TRIFILL(14)
        TRIFILL(15) TRIFILL(16) TRIFILL(17) TRIFILL(18) TRIFILL(19)
        TRIFILL(20) TRIFILL(21) TRIFILL(22) TRIFILL(23) TRIFILL(24)
        TRIFILL(25) TRIFILL(26) TRIFILL(27) TRIFILL(28) TRIFILL(29)
        TRIFILL(30) TRIFILL(31) TRIFILL(32) TRIFILL(33) TRIFILL(34)
        TRIFILL(35) TRIFILL(36) TRIFILL(37) TRIFILL(38) TRIFILL(39)
        TRIFILL(40) TRIFILL(41) TRIFILL(42) TRIFILL(43) TRIFILL(44)
        #undef TRIFILL

        // Unnormalized ascending Horner, KTAY=5:
        // A_j = A_{j-1}*G; R += (1/j!)*A_j
        v2f   A01[MM];
        float A2[MM];
        trow_pk(Tri, A01, R01, R01, 1.0f);
        trow_s (Tri, A2,  R2,  R2,  1.0f);
        trow_pk(Tri, A01, R01, A01, 0.5f);
        trow_s (Tri, A2,  R2,  A2,  0.5f);
        trow_pk(Tri, A01, R01, A01, 0.16666667f);
        trow_s (Tri, A2,  R2,  A2,  0.16666667f);
        trow_pk(Tri, A01, R01, A01, 0.041666668f);
        trow_s (Tri, A2,  R2,  A2,  0.041666668f);
        trow_pk(Tri, A01, R01, A01, 0.0083333338f);
        trow_s (Tri, A2,  R2,  A2,  0.0083333338f);
    }

    // Store segment product: packed pair rows from all lanes, scalar from q<2
    {
        float* dst = &buf_s[seg * MATS];
        float4* d0 = reinterpret_cast<float4*>(dst + p0 * ROWP);
        d0[0] = make_float4(R01[0].x, R01[1].x, R01[2].x, R01[3].x);
        d0[1] = make_float4(R01[4].x, R01[5].x, R01[6].x, R01[7].x);
        d0[2] = make_float4(R01[8].x, R01[9].x, 0.0f, 0.0f);
        float4* d1 = reinterpret_cast<float4*>(dst + (p0 + 1) * ROWP);
        d1[0] = make_float4(R01[0].y, R01[1].y, R01[2].y, R01[3].y);
        d1[1] = make_float4(R01[4].y, R01[5].y, R01[6].y, R01[7].y);
        d1[2] = make_float4(R01[8].y, R01[9].y, 0.0f, 0.0f);
        if (hasS) {
            float4* d2 = reinterpret_cast<float4*>(dst + sr * ROWP);
            d2[0] = make_float4(R2[0], R2[1], R2[2], R2[3]);
            d2[1] = make_float4(R2[4], R2[5], R2[6], R2[7]);
            d2[2] = make_float4(R2[8], R2[9], 0.0f, 0.0f);
        }
    }
    __syncthreads();

    // Pair-style dyadic tree, full 6 levels (64 -> 1 product at slot 0)
    #pragma unroll 1
    for (int span = 2; span <= SEGS; span <<= 1) {
        const int np = SEGS / span;
        if (tid < 2 * np) {
            const int pr = tid >> 1;
            const int pq = tid & 1;
            pair_combine(buf_s, pr * span, pr * span + (span >> 1), pq);
        }
        __syncthreads();
    }

    // Chunk product -> ws, padded 120 floats at (chain*NCHUNK + qt)
    if (tid < 30) {
        const float4 v = reinterpret_cast<const float4*>(buf_s)[tid];
        reinterpret_cast<float4*>(ws)[((size_t)chain * NCHUNK + qt) * 30 + tid] = v;
    }
}

// K2: one block per chain; combine its 4 chunk products (time order)
__global__ __launch_bounds__(256)
void dev_tree4(const float* __restrict__ ws, float* __restrict__ out)
{
    __shared__ __align__(16) float buf_s[4 * MATS];
    const int tid   = threadIdx.x;
    const int chain = blockIdx.x;

    if (tid < 120) {
        const int m  = tid / 30;
        const int o4 = tid - m * 30;
        const float4 v = reinterpret_cast<const float4*>(ws)[((size_t)chain * 4 + m) * 30 + o4];
        reinterpret_cast<float4*>(&buf_s[m * MATS])[o4] = v;
    }
    __syncthreads();

    if (tid < 4)
        pair_combine(buf_s, (tid >> 1) * 2, (tid >> 1) * 2 + 1, tid & 1);
    __syncthreads();
    if (tid < 2)
        pair_combine(buf_s, 0, 2, tid);
    __syncthreads();

    if (tid < 100) {
        const int i = tid / 10;
        const int j = tid - i * 10;
        out[(size_t)chain * 100 + tid] = buf_s[i * ROWP + j];
    }
}

extern "C" void kernel_launch(void* const* d_in, const int* in_sizes, int n_in,
                              void* d_out, int out_size, void* d_ws, size_t ws_size,
                              hipStream_t stream) {
    (void)in_sizes; (void)n_in; (void)out_size; (void)ws_size;
    const float* x = (const float*)d_in[0];  // (64, 2048, 8)
    const float* A = (const float*)d_in[1];  // (2, 8, 10, 10)
    float* out = (float*)d_out;              // (64, 2, 10, 10)
    float* ws  = (float*)d_ws;               // 512 mats * 480 B = 245,760 B

    dev_serial<<<dim3(NCHAIN * NCHUNK), dim3(256), 0, stream>>>(x, A, ws);
    dev_tree4<<<dim3(NCHAIN), dim3(256), 0, stream>>>(ws, out);
}